// Round 3
// baseline (745.378 us; speedup 1.0000x reference)
//
#include <hip/hip_runtime.h>

#define NN 100000
#define NE 1600000
#define EGRID 2048                               // edge kernel blocks (grid-stride)
#define NGRID ((NN + 255) / 256)                 // 391 node blocks

__device__ __forceinline__ float wave_red(float v) {
#pragma unroll
    for (int off = 32; off > 0; off >>= 1) v += __shfl_down(v, off, 64);
    return v;
}

// ================= edge kernel: fully edge-parallel, no sorting ==============
// Gathers x[row], x[col] from the 3.2 MB xin array (L2-resident per r2 FETCH
// evidence); computes edge MLP in-thread; scatter-adds agg[row] via global
// atomics. 2048 blocks -> ~8 blocks/CU vs 391-block bucketed version (11% occ,
// latency-bound at VALUBusy 21%).
template <bool WRITE_EMB, bool NEED_SUM>
__global__ __launch_bounds__(256) void edge_kernel(
    const int* __restrict__ ei,
    const float2* __restrict__ eain,
    float2* __restrict__ eout,
    const float* __restrict__ xin,
    const float* __restrict__ gptr,
    const float* __restrict__ eW1, const float* __restrict__ eB1,
    const float* __restrict__ eW2, const float* __restrict__ eB2,
    float* __restrict__ agg, float* __restrict__ sums)
{
    __shared__ float redE[4][2];
    int tid = threadIdx.x;
    float gval = gptr[0];
    float gterm[16];
#pragma unroll
    for (int q = 0; q < 16; q++) gterm[q] = eB1[q] + gval * eW1[q];

    float t0 = 0.f, t1 = 0.f;
    for (int e = blockIdx.x * 256 + tid; e < NE; e += EGRID * 256) {
        int row = ei[e];
        int col = ei[NE + e];
        float2 ea = eain[e];
        const float4* xr4 = reinterpret_cast<const float4*>(xin + (size_t)row * 8);
        float4 r0 = xr4[0], r1 = xr4[1];
        const float4* xc4 = reinterpret_cast<const float4*>(xin + (size_t)col * 8);
        float4 c0 = xc4[0], c1 = xc4[1];
        float xr[8] = {r0.x, r0.y, r0.z, r0.w, r1.x, r1.y, r1.z, r1.w};
        float xc[8] = {c0.x, c0.y, c0.z, c0.w, c1.x, c1.y, c1.z, c1.w};
        float h[16];
#pragma unroll
        for (int q = 0; q < 16; q++) h[q] = gterm[q];
#pragma unroll
        for (int k = 0; k < 8; k++) {
            float vr = xr[k], vc = xc[k];
#pragma unroll
            for (int q = 0; q < 16; q++) {
                h[q] += vr * eW1[(1 + k) * 16 + q];
                h[q] += vc * eW1[(9 + k) * 16 + q];
            }
        }
#pragma unroll
        for (int q = 0; q < 16; q++) {
            h[q] += ea.x * eW1[17 * 16 + q];
            h[q] += ea.y * eW1[18 * 16 + q];
        }
        float s0 = eB2[0], s1 = eB2[1];
#pragma unroll
        for (int q = 0; q < 16; q++) {
            float rr = fmaxf(h[q], 0.f);
            s0 += rr * eW2[2 * q];
            s1 += rr * eW2[2 * q + 1];
        }
        if (WRITE_EMB) eout[e] = make_float2(s0, s1);
        atomicAdd(&agg[(size_t)row * 2],     s0);
        atomicAdd(&agg[(size_t)row * 2 + 1], s1);
        t0 += s0; t1 += s1;
    }

    if (NEED_SUM) {
        float r0 = wave_red(t0), r1 = wave_red(t1);
        int wave = tid >> 6, lane = tid & 63;
        if (lane == 0) { redE[wave][0] = r0; redE[wave][1] = r1; }
        __syncthreads();
        if (tid == 0) {
            atomicAdd(&sums[0], redE[0][0] + redE[1][0] + redE[2][0] + redE[3][0]);
            atomicAdd(&sums[1], redE[0][1] + redE[1][1] + redE[2][1] + redE[3][1]);
        }
    }
}

// ================= node kernel: per-node MLP on completed agg ================
template <bool NEED_SUM>
__global__ __launch_bounds__(256) void node_kernel(
    const float* __restrict__ xin, const float* __restrict__ agg,
    const float* __restrict__ gptr,
    const float* __restrict__ nW1, const float* __restrict__ nB1,
    const float* __restrict__ nW2, const float* __restrict__ nB2,
    float* __restrict__ xout, float* __restrict__ sums)
{
    __shared__ float redN[4][8];
    int tid = threadIdx.x;
    int n = blockIdx.x * 256 + tid;
    float out[8];
#pragma unroll
    for (int m = 0; m < 8; m++) out[m] = 0.f;

    if (n < NN) {
        float gval = gptr[0];
        float in[11];
        in[0] = gval;
        const float4* xi = reinterpret_cast<const float4*>(xin + (size_t)n * 8);
        float4 a0 = xi[0], a1 = xi[1];
        in[1] = a0.x; in[2] = a0.y; in[3] = a0.z; in[4] = a0.w;
        in[5] = a1.x; in[6] = a1.y; in[7] = a1.z; in[8] = a1.w;
        float2 ag = reinterpret_cast<const float2*>(agg)[n];
        in[9] = ag.x; in[10] = ag.y;

        float h[16];
#pragma unroll
        for (int q = 0; q < 16; q++) h[q] = nB1[q];
#pragma unroll
        for (int k = 0; k < 11; k++) {
            float v = in[k];
#pragma unroll
            for (int q = 0; q < 16; q++) h[q] += v * nW1[k * 16 + q];
        }
#pragma unroll
        for (int m = 0; m < 8; m++) out[m] = nB2[m];
#pragma unroll
        for (int q = 0; q < 16; q++) {
            float hq = fmaxf(h[q], 0.f);
#pragma unroll
            for (int m = 0; m < 8; m++) out[m] += hq * nW2[q * 8 + m];
        }
        float4* xo = reinterpret_cast<float4*>(xout + (size_t)n * 8);
        xo[0] = make_float4(out[0], out[1], out[2], out[3]);
        xo[1] = make_float4(out[4], out[5], out[6], out[7]);
    }
    if (NEED_SUM) {
        float r[8];
#pragma unroll
        for (int m = 0; m < 8; m++) r[m] = wave_red(out[m]);
        int wave = tid >> 6, lane = tid & 63;
        if (lane == 0) {
#pragma unroll
            for (int m = 0; m < 8; m++) redN[wave][m] = r[m];
        }
        __syncthreads();
        if (tid == 0) {
#pragma unroll
            for (int m = 0; m < 8; m++) {
                float s = redN[0][m] + redN[1][m] + redN[2][m] + redN[3][m];
                atomicAdd(&sums[2 + m], s);
            }
        }
    }
}

// ---------------- global block: MLP(11->16->1), single thread ----------------
__global__ void glob_kernel(const float* __restrict__ sums,
                            const float* __restrict__ gold,
                            const float* __restrict__ W1, const float* __restrict__ B1,
                            const float* __restrict__ W2, const float* __restrict__ B2,
                            float* __restrict__ gnew)
{
    if (threadIdx.x == 0 && blockIdx.x == 0) {
        float in[11];
#pragma unroll
        for (int j = 0; j < 8; j++) in[j] = sums[2 + j] * (1.0f / NN);
        in[8] = sums[0] * (1.0f / NE);
        in[9] = sums[1] * (1.0f / NE);
        in[10] = gold[0];
        float acc = B2[0];
#pragma unroll
        for (int j = 0; j < 16; j++) {
            float h = B1[j];
#pragma unroll
            for (int k = 0; k < 11; k++) h += in[k] * W1[k * 16 + j];
            acc += fmaxf(h, 0.f) * W2[j];
        }
        gnew[0] = acc;
    }
}

extern "C" void kernel_launch(void* const* d_in, const int* in_sizes, int n_in,
                              void* d_out, int out_size, void* d_ws, size_t ws_size,
                              hipStream_t stream) {
    const float* x     = (const float*)d_in[0];
    const int*   ei    = (const int*)d_in[1];
    const float* eattr = (const float*)d_in[2];
    const float* g     = (const float*)d_in[3];
    const float* eW1 = (const float*)d_in[4];
    const float* eB1 = (const float*)d_in[5];
    const float* eW2 = (const float*)d_in[6];
    const float* eB2 = (const float*)d_in[7];
    const float* nW1 = (const float*)d_in[8];
    const float* nB1 = (const float*)d_in[9];
    const float* nW2 = (const float*)d_in[10];
    const float* nB2 = (const float*)d_in[11];
    const float* gW1 = (const float*)d_in[12];
    const float* gB1 = (const float*)d_in[13];
    const float* gW2 = (const float*)d_in[14];
    const float* gB2 = (const float*)d_in[15];
    float* out = (float*)d_out;

    char* ws = (char*)d_ws;
    float*  xb0  = (float*)(ws);                   // 3,200,000
    float*  xb1  = (float*)(ws + 3200000);         // 3,200,000 -> 6,400,000
    float*  sums = (float*)(ws + 6400000);         // 2 slabs x 16 floats = 128 B
    float*  g1   = (float*)(ws + 6400128);
    float*  g2   = g1 + 1;
    float*  agg0 = (float*)(ws + 6400256);         // 800,000
    float*  agg1 = (float*)(ws + 7200256);         // 800,000
    float*  agg2 = (float*)(ws + 8000256);         // 800,000 -> 8,800,256
    float2* eemb = (float2*)(ws + 8800256);        // 12,800,000 -> 21,600,256 total

    dim3 blk(256);

    hipMemsetAsync(sums, 0, 128, stream);
    hipMemsetAsync(agg0, 0, 3 * 800000, stream);   // agg0..2 contiguous

    // ---- layer 0: x(d_in) -> xb0; eattr -> eemb ----
    edge_kernel<true, true><<<EGRID, blk, 0, stream>>>(
        ei, (const float2*)eattr, eemb, x, g,
        eW1, eB1, eW2, eB2, agg0, sums);
    node_kernel<true><<<NGRID, blk, 0, stream>>>(
        x, agg0, g, nW1, nB1, nW2, nB2, xb0, sums);
    glob_kernel<<<1, 64, 0, stream>>>(sums, g, gW1, gB1, gW2, gB2, g1);

    // ---- layer 1: xb0 -> xb1; eemb -> eemb (same-index rewrite, safe) ----
    edge_kernel<true, true><<<EGRID, blk, 0, stream>>>(
        ei, eemb, eemb, xb0, g1,
        eW1 + 304, eB1 + 16, eW2 + 32, eB2 + 2, agg1, sums + 16);
    node_kernel<true><<<NGRID, blk, 0, stream>>>(
        xb0, agg1, g1, nW1 + 176, nB1 + 16, nW2 + 128, nB2 + 8, xb1, sums + 16);
    glob_kernel<<<1, 64, 0, stream>>>(sums + 16, g1, gW1 + 176, gB1 + 16, gW2 + 16, gB2 + 1, g2);

    // ---- layer 2: xb1 -> d_out; no emb write, no sums ----
    edge_kernel<false, false><<<EGRID, blk, 0, stream>>>(
        ei, eemb, nullptr, xb1, g2,
        eW1 + 608, eB1 + 32, eW2 + 64, eB2 + 4, agg2, sums);
    node_kernel<false><<<NGRID, blk, 0, stream>>>(
        xb1, agg2, g2, nW1 + 352, nB1 + 32, nW2 + 256, nB2 + 16, out, sums);
}

// Round 4
// 680.477 us; speedup vs baseline: 1.0954x; 1.0954x over previous
//
#include <hip/hip_runtime.h>

#define NN 100000
#define NE 1600000
#define CH 4096                                  // edges per chunk
#define NCHUNK ((NE + CH - 1) / CH)              // 391
#define BUCK 64                                  // nodes per bucket
#define NBUCK ((NN + BUCK - 1) / BUCK)           // 1563 blocks -> ~6 blocks/CU

__device__ __forceinline__ float wave_red(float v) {
#pragma unroll
    for (int off = 32; off > 0; off >>= 1) v += __shfl_down(v, off, 64);
    return v;
}

// ---------------- build phase: bucket sort, zero global atomics --------------
__global__ __launch_bounds__(256) void hist_kernel(
    const int* __restrict__ ei, int* __restrict__ hist)
{
    __shared__ int h[NBUCK];                     // 6252 B
    int t = threadIdx.x, c = blockIdx.x;
    for (int b = t; b < NBUCK; b += 256) h[b] = 0;
    __syncthreads();
    int base = c * CH;
    for (int i = t; i < CH; i += 256) {
        int e = base + i;
        if (e < NE) atomicAdd(&h[ei[e] >> 6], 1);
    }
    __syncthreads();
    for (int b = t; b < NBUCK; b += 256) hist[c * NBUCK + b] = h[b];
}

__global__ __launch_bounds__(512) void bscan_kernel(
    const int* __restrict__ hist, int* __restrict__ baseT, int* __restrict__ colTotal)
{
    __shared__ int buf[2][512];
    int b = blockIdx.x, t = threadIdx.x;
    int v = (t < NCHUNK) ? hist[t * NBUCK + b] : 0;
    buf[0][t] = v;
    __syncthreads();
    int src = 0;
    for (int d = 1; d < 512; d <<= 1) {
        int nv = buf[src][t] + ((t >= d) ? buf[src][t - d] : 0);
        buf[src ^ 1][t] = nv;
        src ^= 1;
        __syncthreads();
    }
    if (t < NCHUNK) baseT[b * NCHUNK + t] = buf[src][t] - v;   // exclusive over chunks
    if (t == NCHUNK - 1) colTotal[b] = buf[src][t];
}

// exclusive scan over NBUCK=1563 bucket totals (2048-wide, 2 elems/thread)
__global__ __launch_bounds__(1024) void boff_kernel(
    const int* __restrict__ colTotal, int* __restrict__ b_off)
{
    __shared__ int buf[2][2048];                 // 16 KB
    int t = threadIdx.x;
    for (int i = t; i < 2048; i += 1024)
        buf[0][i] = (i < NBUCK) ? colTotal[i] : 0;
    __syncthreads();
    int src = 0;
    for (int d = 1; d < 2048; d <<= 1) {
        for (int i = t; i < 2048; i += 1024) {
            int v = buf[src][i];
            if (i >= d) v += buf[src][i - d];
            buf[src ^ 1][i] = v;
        }
        src ^= 1;
        __syncthreads();
    }
    for (int i = t; i < 2048; i += 1024)
        if (i < NBUCK) b_off[i] = buf[src][i] - colTotal[i];
    if (t == 0) b_off[NBUCK] = buf[src][NBUCK - 1];            // = NE
}

// record split: immutable 4B key (li<<17 | col), mutable 8B float2 (ea / emb).
__global__ __launch_bounds__(256) void fillb_kernel(
    const int* __restrict__ ei, const float* __restrict__ eattr,
    const int* __restrict__ baseT, const int* __restrict__ b_off,
    int* __restrict__ key, float2* __restrict__ recEA)
{
    __shared__ int sslot[NBUCK];
    int t = threadIdx.x, c = blockIdx.x;
    for (int b = t; b < NBUCK; b += 256)
        sslot[b] = b_off[b] + baseT[b * NCHUNK + c];
    __syncthreads();
    int base = c * CH;
    for (int i = t; i < CH; i += 256) {
        int e = base + i;
        if (e < NE) {
            int row = ei[e];
            int slot = atomicAdd(&sslot[row >> 6], 1);
            float2 ea = reinterpret_cast<const float2*>(eattr)[e];
            key[slot] = ((row & (BUCK - 1)) << 17) | ei[NE + e];
            recEA[slot] = ea;
        }
    }
}

// ============ FUSED layer kernel: edge MLP + node MLP, LDS aggregation =======
// BUCK=64 (1563 blocks, ~6 blocks/CU) fixes the 11%-occupancy latency bound;
// per-edge gather is x[col] (32 B from 3.2 MB, per-XCD-L2-resident per r2
// FETCH evidence) so the r1 L2-thrash mode (6.4 MB Pc) cannot recur.
// Aggregation stays in LDS: r3 proved global scatter-atomics write through
// to HBM (~31 B/atomic -> 100 MB/dispatch).
template <bool WRITE_REC, bool NEED_SUM>
__global__ __launch_bounds__(256) void fused_kernel(
    const int* __restrict__ key, float2* __restrict__ recEA,
    const int* __restrict__ b_off,
    const float* __restrict__ gptr,
    const float* __restrict__ eW1, const float* __restrict__ eB1,
    const float* __restrict__ eW2, const float* __restrict__ eB2,
    const float* __restrict__ xin,
    const float* __restrict__ nW1, const float* __restrict__ nB1,
    const float* __restrict__ nW2, const float* __restrict__ nB2,
    float* __restrict__ xout, float* __restrict__ sums)
{
    __shared__ float sPrT[16 * BUCK];            // 4 KB, transposed: [q*64+li]
    __shared__ float sagg[BUCK][2];
    __shared__ float redE[4][2];
    int tid = threadIdx.x;
    if (tid < 2 * BUCK) ((float*)sagg)[tid] = 0.f;

    int n0 = blockIdx.x * BUCK;
    float gval = gptr[0];
    float xv[8];
    bool own = (tid < BUCK) && (n0 + tid < NN);
    if (own) {
        // row-projection for own node, computed in-block (128 FMAs, once);
        // x row kept in registers for the node phase.
        const float4* xi = reinterpret_cast<const float4*>(xin + (size_t)(n0 + tid) * 8);
        float4 a0 = xi[0], a1 = xi[1];
        xv[0] = a0.x; xv[1] = a0.y; xv[2] = a0.z; xv[3] = a0.w;
        xv[4] = a1.x; xv[5] = a1.y; xv[6] = a1.z; xv[7] = a1.w;
        float pr[16];
#pragma unroll
        for (int q = 0; q < 16; q++) pr[q] = 0.f;
#pragma unroll
        for (int k = 0; k < 8; k++) {
            float v = xv[k];
#pragma unroll
            for (int q = 0; q < 16; q++) pr[q] += v * eW1[(1 + k) * 16 + q];
        }
#pragma unroll
        for (int q = 0; q < 16; q++) sPrT[q * BUCK + tid] = pr[q];
    }
    __syncthreads();

    int e0 = b_off[blockIdx.x], e1 = b_off[blockIdx.x + 1];

    float gterm[16];
#pragma unroll
    for (int q = 0; q < 16; q++) gterm[q] = eB1[q] + gval * eW1[q];

    float t0 = 0.f, t1 = 0.f;
    for (int e = e0 + tid; e < e1; e += 256) {
        int k = key[e];
        int col = k & 0x1FFFF;
        int li = k >> 17;
        float2 ea = recEA[e];
        const float4* xc4 = reinterpret_cast<const float4*>(xin + (size_t)col * 8);
        float4 c0 = xc4[0], c1 = xc4[1];
        float xc[8] = {c0.x, c0.y, c0.z, c0.w, c1.x, c1.y, c1.z, c1.w};
        float h[16];
#pragma unroll
        for (int q = 0; q < 16; q++) h[q] = gterm[q] + sPrT[q * BUCK + li];
#pragma unroll
        for (int kk = 0; kk < 8; kk++) {
            float v = xc[kk];
#pragma unroll
            for (int q = 0; q < 16; q++) h[q] += v * eW1[(9 + kk) * 16 + q];
        }
#pragma unroll
        for (int q = 0; q < 16; q++) {
            h[q] += ea.x * eW1[17 * 16 + q];
            h[q] += ea.y * eW1[18 * 16 + q];
        }
        float s0 = eB2[0], s1 = eB2[1];
#pragma unroll
        for (int q = 0; q < 16; q++) {
            float rr = fmaxf(h[q], 0.f);
            s0 += rr * eW2[2 * q];
            s1 += rr * eW2[2 * q + 1];
        }
        if (WRITE_REC) recEA[e] = make_float2(s0, s1);
        atomicAdd(&sagg[li][0], s0);
        atomicAdd(&sagg[li][1], s1);
        t0 += s0; t1 += s1;
    }

    if (NEED_SUM) {
        float r0 = wave_red(t0), r1 = wave_red(t1);
        int wave = tid >> 6, lane = tid & 63;
        if (lane == 0) { redE[wave][0] = r0; redE[wave][1] = r1; }
    }
    __syncthreads();   // sagg complete (and redE visible)
    if (NEED_SUM && tid == 0) {
        atomicAdd(&sums[0], redE[0][0] + redE[1][0] + redE[2][0] + redE[3][0]);
        atomicAdd(&sums[1], redE[0][1] + redE[1][1] + redE[2][1] + redE[3][1]);
    }

    // ---------------- phase 2: node MLP (owner threads 0..63) ----------------
    float out[8];
#pragma unroll
    for (int m = 0; m < 8; m++) out[m] = 0.f;

    if (own) {
        int n = n0 + tid;
        float in[11];
        in[0] = gval;
#pragma unroll
        for (int k = 0; k < 8; k++) in[1 + k] = xv[k];
        in[9] = sagg[tid][0]; in[10] = sagg[tid][1];

        float h[16];
#pragma unroll
        for (int q = 0; q < 16; q++) h[q] = nB1[q];
#pragma unroll
        for (int k = 0; k < 11; k++) {
            float v = in[k];
#pragma unroll
            for (int q = 0; q < 16; q++) h[q] += v * nW1[k * 16 + q];
        }
#pragma unroll
        for (int m = 0; m < 8; m++) out[m] = nB2[m];
#pragma unroll
        for (int q = 0; q < 16; q++) {
            float hq = fmaxf(h[q], 0.f);
#pragma unroll
            for (int m = 0; m < 8; m++) out[m] += hq * nW2[q * 8 + m];
        }
        float4* xo = reinterpret_cast<float4*>(xout + (size_t)n * 8);
        xo[0] = make_float4(out[0], out[1], out[2], out[3]);
        xo[1] = make_float4(out[4], out[5], out[6], out[7]);
    }
    if (NEED_SUM) {
        // only wave 0 holds nonzero out; its wave_red covers all 64 owners
        float r[8];
#pragma unroll
        for (int m = 0; m < 8; m++) r[m] = wave_red(out[m]);
        if (tid == 0) {
#pragma unroll
            for (int m = 0; m < 8; m++) atomicAdd(&sums[2 + m], r[m]);
        }
    }
}

// ---------------- global block: MLP(11->16->1), single thread ----------------
__global__ void glob_kernel(const float* __restrict__ sums,
                            const float* __restrict__ gold,
                            const float* __restrict__ W1, const float* __restrict__ B1,
                            const float* __restrict__ W2, const float* __restrict__ B2,
                            float* __restrict__ gnew)
{
    if (threadIdx.x == 0 && blockIdx.x == 0) {
        float in[11];
#pragma unroll
        for (int j = 0; j < 8; j++) in[j] = sums[2 + j] * (1.0f / NN);
        in[8] = sums[0] * (1.0f / NE);
        in[9] = sums[1] * (1.0f / NE);
        in[10] = gold[0];
        float acc = B2[0];
#pragma unroll
        for (int j = 0; j < 16; j++) {
            float h = B1[j];
#pragma unroll
            for (int k = 0; k < 11; k++) h += in[k] * W1[k * 16 + j];
            acc += fmaxf(h, 0.f) * W2[j];
        }
        gnew[0] = acc;
    }
}

extern "C" void kernel_launch(void* const* d_in, const int* in_sizes, int n_in,
                              void* d_out, int out_size, void* d_ws, size_t ws_size,
                              hipStream_t stream) {
    const float* x     = (const float*)d_in[0];
    const int*   ei    = (const int*)d_in[1];
    const float* eattr = (const float*)d_in[2];
    const float* g     = (const float*)d_in[3];
    const float* eW1 = (const float*)d_in[4];
    const float* eB1 = (const float*)d_in[5];
    const float* eW2 = (const float*)d_in[6];
    const float* eB2 = (const float*)d_in[7];
    const float* nW1 = (const float*)d_in[8];
    const float* nB1 = (const float*)d_in[9];
    const float* nW2 = (const float*)d_in[10];
    const float* nB2 = (const float*)d_in[11];
    const float* gW1 = (const float*)d_in[12];
    const float* gB1 = (const float*)d_in[13];
    const float* gW2 = (const float*)d_in[14];
    const float* gB2 = (const float*)d_in[15];
    float* out = (float*)d_out;

    char* ws = (char*)d_ws;
    float*  xb0   = (float*)(ws);                  // 3,200,000
    float*  xb1   = (float*)(ws + 3200000);        // 3,200,000 -> 6,400,000
    int*    b_off = (int*)  (ws + 6400000);        // 1564*4 = 6,256 -> pad 6,400
    float*  sums  = (float*)(ws + 6406400);        // 2 slabs x 16 floats = 128 B
    float*  g1    = (float*)(ws + 6406528);
    float*  g2    = g1 + 1;
    int*    key   = (int*)  (ws + 6406656);        // 6,400,000 -> 12,806,656
    float2* recEA = (float2*)(ws + 12806656);      // 12,800,000 -> 25,606,656 total
    // build-phase temporaries alias xb0/xb1 (dead before fused L0 writes xb0):
    int*    hist     = (int*)ws;                           // 391*1563*4 = 2,444,532
    int*    baseT    = (int*)(ws + 2444800);               // 2,444,532
    int*    colTotal = (int*)(ws + 4889600);               // 6,252  (all < 6.4 MB)

    dim3 blk(256);
    dim3 cgrid(NCHUNK);                            // 391 chunks
    dim3 bgrid(NBUCK);                             // 1563 buckets

    // ---- bucket-sort build (no global atomics) ----
    hipMemsetAsync(sums, 0, 128, stream);
    hist_kernel<<<cgrid, blk, 0, stream>>>(ei, hist);
    bscan_kernel<<<bgrid, 512, 0, stream>>>(hist, baseT, colTotal);
    boff_kernel<<<1, 1024, 0, stream>>>(colTotal, b_off);
    fillb_kernel<<<cgrid, blk, 0, stream>>>(ei, eattr, baseT, b_off, key, recEA);

    // ---- layer 0: x(d_in) -> xb0; recEA: ea -> L0 edge emb ----
    fused_kernel<true, true><<<bgrid, blk, 0, stream>>>(
        key, recEA, b_off, g,
        eW1, eB1, eW2, eB2,
        x, nW1, nB1, nW2, nB2,
        xb0, sums);
    glob_kernel<<<1, 64, 0, stream>>>(sums, g, gW1, gB1, gW2, gB2, g1);

    // ---- layer 1: xb0 -> xb1; recEA: L0 -> L1 emb ----
    fused_kernel<true, true><<<bgrid, blk, 0, stream>>>(
        key, recEA, b_off, g1,
        eW1 + 304, eB1 + 16, eW2 + 32, eB2 + 2,
        xb0, nW1 + 176, nB1 + 16, nW2 + 128, nB2 + 8,
        xb1, sums + 16);
    glob_kernel<<<1, 64, 0, stream>>>(sums + 16, g1, gW1 + 176, gB1 + 16, gW2 + 16, gB2 + 1, g2);

    // ---- layer 2: xb1 -> d_out; no emb rewrite, no sums ----
    fused_kernel<false, false><<<bgrid, blk, 0, stream>>>(
        key, recEA, b_off, g2,
        eW1 + 608, eB1 + 32, eW2 + 64, eB2 + 4,
        xb1, nW1 + 352, nB1 + 32, nW2 + 256, nB2 + 16,
        out, sums);
}

// Round 5
// 331.729 us; speedup vs baseline: 2.2469x; 2.0513x over previous
//
#include <hip/hip_runtime.h>

#define NN 100000
#define NE 1600000
#define CH 4096                                  // edges per chunk
#define NCHUNK ((NE + CH - 1) / CH)              // 391
#define NBUCK ((NN + 255) / 256)                 // 391 (256-node buckets = fused blocks)

__device__ __forceinline__ float wave_red(float v) {
#pragma unroll
    for (int off = 32; off > 0; off >>= 1) v += __shfl_down(v, off, 64);
    return v;
}

// ---------------- build phase: bucket sort, zero global atomics --------------
__global__ __launch_bounds__(256) void hist_kernel(
    const int* __restrict__ ei, int* __restrict__ hist)
{
    __shared__ int h[NBUCK];
    int t = threadIdx.x, c = blockIdx.x;
    for (int b = t; b < NBUCK; b += 256) h[b] = 0;
    __syncthreads();
    int base = c * CH;
    for (int i = t; i < CH; i += 256) {
        int e = base + i;
        if (e < NE) atomicAdd(&h[ei[e] >> 8], 1);
    }
    __syncthreads();
    for (int b = t; b < NBUCK; b += 256) hist[c * NBUCK + b] = h[b];
}

__global__ __launch_bounds__(512) void bscan_kernel(
    const int* __restrict__ hist, int* __restrict__ baseT, int* __restrict__ colTotal)
{
    __shared__ int buf[2][512];
    int b = blockIdx.x, t = threadIdx.x;
    int v = (t < NCHUNK) ? hist[t * NBUCK + b] : 0;
    buf[0][t] = v;
    __syncthreads();
    int src = 0;
    for (int d = 1; d < 512; d <<= 1) {
        int nv = buf[src][t] + ((t >= d) ? buf[src][t - d] : 0);
        buf[src ^ 1][t] = nv;
        src ^= 1;
        __syncthreads();
    }
    if (t < NCHUNK) baseT[b * NCHUNK + t] = buf[src][t] - v;   // exclusive over chunks
    if (t == NCHUNK - 1) colTotal[b] = buf[src][t];
}

__global__ __launch_bounds__(512) void boff_kernel(
    const int* __restrict__ colTotal, int* __restrict__ b_off)
{
    __shared__ int buf[2][512];
    int t = threadIdx.x;
    int v = (t < NBUCK) ? colTotal[t] : 0;
    buf[0][t] = v;
    __syncthreads();
    int src = 0;
    for (int d = 1; d < 512; d <<= 1) {
        int nv = buf[src][t] + ((t >= d) ? buf[src][t - d] : 0);
        buf[src ^ 1][t] = nv;
        src ^= 1;
        __syncthreads();
    }
    if (t < NBUCK) b_off[t] = buf[src][t] - v;
    if (t == NBUCK - 1) b_off[NBUCK] = buf[src][t];            // = NE
}

__global__ __launch_bounds__(256) void fillb_kernel(
    const int* __restrict__ ei, const float* __restrict__ eattr,
    const int* __restrict__ baseT, const int* __restrict__ b_off,
    float4* __restrict__ rec)
{
    __shared__ int sslot[NBUCK];
    int t = threadIdx.x, c = blockIdx.x;
    for (int b = t; b < NBUCK; b += 256)
        sslot[b] = b_off[b] + baseT[b * NCHUNK + c];
    __syncthreads();
    int base = c * CH;
    for (int i = t; i < CH; i += 256) {
        int e = base + i;
        if (e < NE) {
            int row = ei[e];
            int slot = atomicAdd(&sslot[row >> 8], 1);
            float2 ea = reinterpret_cast<const float2*>(eattr)[e];
            float4 v;
            v.x = __int_as_float(row);
            v.y = __int_as_float(ei[NE + e]);
            v.z = ea.x; v.w = ea.y;
            rec[slot] = v;
        }
    }
}

// ============ FUSED layer kernel: identical algorithm to r2, 1024 threads ====
// r2 (256 thr): 391 blocks -> ~6 waves/CU, VALU 21%, HBM 8%, latency-bound.
// r4 proved shrinking buckets to add blocks costs 2.7x (per-block structure).
// So: same 391 blocks / 256-node buckets, but 16 waves per block -> 16-32
// waves/CU. Edge loop stays long (~4 iter/thread over ~4096 edges); fixed
// phases stay amortized; request-concurrency regime stays near r2's.
template <bool WRITE_REC, bool NEED_SUM>
__global__ __launch_bounds__(1024, 4) void fused_kernel(
    float4* __restrict__ rec, const int* __restrict__ b_off,
    const float* __restrict__ gptr,
    const float* __restrict__ eW1, const float* __restrict__ eB1,
    const float* __restrict__ eW2, const float* __restrict__ eB2,
    const float* __restrict__ xin,
    const float* __restrict__ nW1, const float* __restrict__ nB1,
    const float* __restrict__ nW2, const float* __restrict__ nB2,
    float* __restrict__ xout, float* __restrict__ sums)
{
    __shared__ float sPrT[16 * 256];             // 16 KB, transposed: [q*256+li]
    __shared__ float sagg[256][2];               // 2 KB
    __shared__ float redE[16][2];
    __shared__ float redN[4][8];
    int tid = threadIdx.x;
    if (tid < 512) ((float*)sagg)[tid] = 0.f;

    int n0 = blockIdx.x * 256;
    bool own = (tid < 256) && (n0 + tid < NN);
    if (own) {
        // row-projection for own node, computed in-block (128 FMAs, once)
        const float4* xi = reinterpret_cast<const float4*>(xin + (size_t)(n0 + tid) * 8);
        float4 a0 = xi[0], a1 = xi[1];
        float xv[8] = {a0.x, a0.y, a0.z, a0.w, a1.x, a1.y, a1.z, a1.w};
        float pr[16];
#pragma unroll
        for (int q = 0; q < 16; q++) pr[q] = 0.f;
#pragma unroll
        for (int k = 0; k < 8; k++) {
            float v = xv[k];
#pragma unroll
            for (int q = 0; q < 16; q++) pr[q] += v * eW1[(1 + k) * 16 + q];
        }
#pragma unroll
        for (int q = 0; q < 16; q++) sPrT[q * 256 + tid] = pr[q];
    }
    __syncthreads();

    int e0 = b_off[blockIdx.x], e1 = b_off[blockIdx.x + 1];

    float gval = gptr[0];
    float gterm[16];
#pragma unroll
    for (int q = 0; q < 16; q++) gterm[q] = eB1[q] + gval * eW1[q];

    float t0 = 0.f, t1 = 0.f;
    for (int e = e0 + tid; e < e1; e += 1024) {
        float4 r = rec[e];
        int row = __float_as_int(r.x);
        int col = __float_as_int(r.y);
        float ea0 = r.z, ea1 = r.w;
        int li = row - n0;
        const float4* xc4 = reinterpret_cast<const float4*>(xin + (size_t)col * 8);
        float4 c0 = xc4[0], c1 = xc4[1];
        float xc[8] = {c0.x, c0.y, c0.z, c0.w, c1.x, c1.y, c1.z, c1.w};
        float h[16];
#pragma unroll
        for (int q = 0; q < 16; q++) h[q] = gterm[q] + sPrT[q * 256 + li];
#pragma unroll
        for (int k = 0; k < 8; k++) {
            float v = xc[k];
#pragma unroll
            for (int q = 0; q < 16; q++) h[q] += v * eW1[(9 + k) * 16 + q];
        }
#pragma unroll
        for (int q = 0; q < 16; q++) {
            h[q] += ea0 * eW1[17 * 16 + q];
            h[q] += ea1 * eW1[18 * 16 + q];
        }
        float s0 = eB2[0], s1 = eB2[1];
#pragma unroll
        for (int q = 0; q < 16; q++) {
            float rr = fmaxf(h[q], 0.f);
            s0 += rr * eW2[2 * q];
            s1 += rr * eW2[2 * q + 1];
        }
        if (WRITE_REC) {
            float4 w;
            w.x = r.x; w.y = r.y; w.z = s0; w.w = s1;
            rec[e] = w;
        }
        atomicAdd(&sagg[li][0], s0);
        atomicAdd(&sagg[li][1], s1);
        t0 += s0; t1 += s1;
    }

    if (NEED_SUM) {
        float r0 = wave_red(t0);
        float r1 = wave_red(t1);
        int wave = tid >> 6, lane = tid & 63;
        if (lane == 0) { redE[wave][0] = r0; redE[wave][1] = r1; }
    }
    __syncthreads();   // sagg complete (and redE visible)
    if (NEED_SUM && tid == 0) {
        float s0 = 0.f, s1 = 0.f;
#pragma unroll
        for (int w = 0; w < 16; w++) { s0 += redE[w][0]; s1 += redE[w][1]; }
        atomicAdd(&sums[0], s0);
        atomicAdd(&sums[1], s1);
    }

    // ---------------- phase 2: node MLP (threads 0..255) ----------------
    float out[8];
#pragma unroll
    for (int m = 0; m < 8; m++) out[m] = 0.f;

    if (own) {
        int n = n0 + tid;
        float in[11];
        in[0] = gval;
        const float4* xi = reinterpret_cast<const float4*>(xin + (size_t)n * 8);
        float4 a0 = xi[0], a1 = xi[1];
        in[1] = a0.x; in[2] = a0.y; in[3] = a0.z; in[4] = a0.w;
        in[5] = a1.x; in[6] = a1.y; in[7] = a1.z; in[8] = a1.w;
        in[9] = sagg[tid][0]; in[10] = sagg[tid][1];

        float h[16];
#pragma unroll
        for (int q = 0; q < 16; q++) h[q] = nB1[q];
#pragma unroll
        for (int k = 0; k < 11; k++) {
            float v = in[k];
#pragma unroll
            for (int q = 0; q < 16; q++) h[q] += v * nW1[k * 16 + q];
        }
#pragma unroll
        for (int m = 0; m < 8; m++) out[m] = nB2[m];
#pragma unroll
        for (int q = 0; q < 16; q++) {
            float hq = fmaxf(h[q], 0.f);
#pragma unroll
            for (int m = 0; m < 8; m++) out[m] += hq * nW2[q * 8 + m];
        }
        float4* xo = reinterpret_cast<float4*>(xout + (size_t)n * 8);
        xo[0] = make_float4(out[0], out[1], out[2], out[3]);
        xo[1] = make_float4(out[4], out[5], out[6], out[7]);
    }
    if (NEED_SUM) {
        // owners are waves 0..3 only; reduce within those waves
        float r[8];
#pragma unroll
        for (int m = 0; m < 8; m++) r[m] = wave_red(out[m]);
        int wave = tid >> 6, lane = tid & 63;
        if (wave < 4 && lane == 0) {
#pragma unroll
            for (int m = 0; m < 8; m++) redN[wave][m] = r[m];
        }
        __syncthreads();
        if (tid == 0) {
#pragma unroll
            for (int m = 0; m < 8; m++) {
                float s = redN[0][m] + redN[1][m] + redN[2][m] + redN[3][m];
                atomicAdd(&sums[2 + m], s);
            }
        }
    }
}

// ---------------- global block: MLP(11->16->1), single thread ----------------
__global__ void glob_kernel(const float* __restrict__ sums,
                            const float* __restrict__ gold,
                            const float* __restrict__ W1, const float* __restrict__ B1,
                            const float* __restrict__ W2, const float* __restrict__ B2,
                            float* __restrict__ gnew)
{
    if (threadIdx.x == 0 && blockIdx.x == 0) {
        float in[11];
#pragma unroll
        for (int j = 0; j < 8; j++) in[j] = sums[2 + j] * (1.0f / NN);
        in[8] = sums[0] * (1.0f / NE);
        in[9] = sums[1] * (1.0f / NE);
        in[10] = gold[0];
        float acc = B2[0];
#pragma unroll
        for (int j = 0; j < 16; j++) {
            float h = B1[j];
#pragma unroll
            for (int k = 0; k < 11; k++) h += in[k] * W1[k * 16 + j];
            acc += fmaxf(h, 0.f) * W2[j];
        }
        gnew[0] = acc;
    }
}

extern "C" void kernel_launch(void* const* d_in, const int* in_sizes, int n_in,
                              void* d_out, int out_size, void* d_ws, size_t ws_size,
                              hipStream_t stream) {
    const float* x     = (const float*)d_in[0];
    const int*   ei    = (const int*)d_in[1];
    const float* eattr = (const float*)d_in[2];
    const float* g     = (const float*)d_in[3];
    const float* eW1 = (const float*)d_in[4];
    const float* eB1 = (const float*)d_in[5];
    const float* eW2 = (const float*)d_in[6];
    const float* eB2 = (const float*)d_in[7];
    const float* nW1 = (const float*)d_in[8];
    const float* nB1 = (const float*)d_in[9];
    const float* nW2 = (const float*)d_in[10];
    const float* nB2 = (const float*)d_in[11];
    const float* gW1 = (const float*)d_in[12];
    const float* gB1 = (const float*)d_in[13];
    const float* gW2 = (const float*)d_in[14];
    const float* gB2 = (const float*)d_in[15];
    float* out = (float*)d_out;

    char* ws = (char*)d_ws;
    float*  xb0   = (float*)(ws);                  // 3,200,000
    float*  xb1   = (float*)(ws + 3200000);        // 3,200,000 -> 6,400,000
    int*    b_off = (int*)  (ws + 6400000);        // 392*4 = 1,568 -> pad 1,600
    float*  sums  = (float*)(ws + 6401600);        // 2 slabs x 16 floats = 128 B
    float*  g1    = (float*)(ws + 6401728);
    float*  g2    = g1 + 1;
    float4* rec   = (float4*)(ws + 6401792);       // 25,600,000 -> 32,001,792 total
    // build-phase temporaries alias xb1 (dead until layer-1 phase 2):
    int*    hist     = (int*)xb1;                          // 391*391*4 = 611,524
    int*    baseT    = (int*)((char*)xb1 + 611584);        // 611,524
    int*    colTotal = (int*)((char*)xb1 + 1223168);       // 1,564

    dim3 blk(256);
    dim3 fblk(1024);
    dim3 cgrid(NCHUNK);                            // 391 chunks
    dim3 bgrid(NBUCK);                             // 391 buckets

    // ---- bucket-sort build (no global atomics) ----
    hipMemsetAsync(sums, 0, 128, stream);
    hist_kernel<<<cgrid, blk, 0, stream>>>(ei, hist);
    bscan_kernel<<<bgrid, 512, 0, stream>>>(hist, baseT, colTotal);
    boff_kernel<<<1, 512, 0, stream>>>(colTotal, b_off);
    fillb_kernel<<<cgrid, blk, 0, stream>>>(ei, eattr, baseT, b_off, rec);

    // ---- layer 0: x(d_in) -> xb0; rec.zw: ea -> L0 edge emb ----
    fused_kernel<true, true><<<bgrid, fblk, 0, stream>>>(
        rec, b_off, g,
        eW1, eB1, eW2, eB2,
        x, nW1, nB1, nW2, nB2,
        xb0, sums);
    glob_kernel<<<1, 64, 0, stream>>>(sums, g, gW1, gB1, gW2, gB2, g1);

    // ---- layer 1: xb0 -> xb1; rec.zw: L0 -> L1 emb ----
    fused_kernel<true, true><<<bgrid, fblk, 0, stream>>>(
        rec, b_off, g1,
        eW1 + 304, eB1 + 16, eW2 + 32, eB2 + 2,
        xb0, nW1 + 176, nB1 + 16, nW2 + 128, nB2 + 8,
        xb1, sums + 16);
    glob_kernel<<<1, 64, 0, stream>>>(sums + 16, g1, gW1 + 176, gB1 + 16, gW2 + 16, gB2 + 1, g2);

    // ---- layer 2: xb1 -> d_out; no rec rewrite, no sums ----
    fused_kernel<false, false><<<bgrid, fblk, 0, stream>>>(
        rec, b_off, g2,
        eW1 + 608, eB1 + 32, eW2 + 64, eB2 + 4,
        xb1, nW1 + 352, nB1 + 32, nW2 + 256, nB2 + 16,
        out, sums);
}